// Round 8
// baseline (409.646 us; speedup 1.0000x reference)
//
#include <hip/hip_runtime.h>
#include <hip/hip_cooperative_groups.h>
#include <hip/hip_bf16.h>
#include <stdint.h>

namespace cg = cooperative_groups;

#define SEQ   2048
#define DIM   512
#define BATCH 4

typedef __attribute__((ext_vector_type(8))) short  short8;
typedef __attribute__((ext_vector_type(4))) float  floatx4;

static __device__ __forceinline__ unsigned short f2b(float f) {
  return __builtin_bit_cast(unsigned short, __float2bfloat16(f));
}

// async 16B/lane global->LDS (global_load_lds_dwordx4)
static __device__ __forceinline__ void gll16(const void* g, void* l) {
  __builtin_amdgcn_global_load_lds(
      (__attribute__((address_space(1))) void*)(uintptr_t)g,
      (__attribute__((address_space(3))) void*)l, 16, 0, 0);
}

// 128 x (NF*32) tile GEMM mainloop, BK=32, 256 threads (4 waves as 2x2),
// double-buffered LDS with issue-early staging.
template <int NF>
__device__ __forceinline__ void gemm_dbuf(
    const __hip_bfloat16* __restrict__ A, int lda,
    const __hip_bfloat16* __restrict__ Bt, int ldb,
    int kIters, char* lds, floatx4 (&acc)[4][NF])
{
  constexpr int NT  = NF * 32;
  constexpr int BUF = 8192 + NT * 64;
  const int tid  = threadIdx.x;
  const int lane = tid & 63;
  const int row  = tid >> 2;   // 0..63
  const int kc   = tid & 3;
  const int wm   = ((tid >> 6) & 1) * 64;
  const int wn   = ((tid >> 6) >> 1) * (NF * 16);

  auto stage = [&](int p, int kt) {
    const int k0 = kt * 32 + kc * 8;
    char* bA = lds + p * BUF;
    char* bB = bA + 8192;
    gll16(A  + (size_t)row        * lda + k0, bA + tid * 16);
    gll16(A  + (size_t)(row + 64) * lda + k0, bA + 4096 + tid * 16);
    gll16(Bt + (size_t)row        * ldb + k0, bB + tid * 16);
    if (NF == 4)
      gll16(Bt + (size_t)(row + 64) * ldb + k0, bB + 4096 + tid * 16);
  };

  stage(0, 0);
  __syncthreads();

  for (int kt = 0; kt < kIters; ++kt) {
    const int p = kt & 1;
    const char* bA = lds + p * BUF;
    const char* bB = bA + 8192;

    short8 af[4], bf[NF];
#pragma unroll
    for (int i = 0; i < 4; ++i)
      af[i] = *(const short8*)(bA + (wm + i * 16 + (lane & 15)) * 64 + (lane >> 4) * 16);
#pragma unroll
    for (int j = 0; j < NF; ++j)
      bf[j] = *(const short8*)(bB + (wn + j * 16 + (lane & 15)) * 64 + (lane >> 4) * 16);

    if (kt + 1 < kIters) stage(1 - p, kt + 1);

#pragma unroll
    for (int i = 0; i < 4; ++i)
#pragma unroll
      for (int j = 0; j < NF; ++j)
        acc[i][j] = __builtin_amdgcn_mfma_f32_16x16x32_bf16(af[i], bf[j], acc[i][j], 0, 0, 0);

    __syncthreads();
  }
}

// ===================== phase bodies (shared coop/fallback) =================

__device__ __forceinline__ void phase0_body(
    int blk, const float* __restrict__ X, const float* __restrict__ Wq,
    const float* __restrict__ Wk, const float* __restrict__ Wv,
    __hip_bfloat16* __restrict__ Xb, __hip_bfloat16* __restrict__ Wt3,
    float* __restrict__ rowsum)
{
  const int tg = blk * 256 + threadIdx.x;    // 0..131071
#pragma unroll
  for (int it = 0; it < 8; ++it) {           // X: 1,048,576 float4
    const int i = it * 131072 + tg;
    float4 v = ((const float4*)X)[i];
    ushort4 o;
    o.x = f2b(v.x); o.y = f2b(v.y); o.z = f2b(v.z); o.w = f2b(v.w);
    ((ushort4*)Xb)[i] = o;
  }
#pragma unroll
  for (int it = 0; it < 6; ++it) {           // W -> Wt3 transpose: 786,432
    const int id = it * 131072 + tg;
    const int z = id >> 18, rem = id & 262143;
    const int k = rem >> 9, n = rem & 511;
    const float* W = (z == 0) ? Wq : (z == 1) ? Wk : Wv;
    Wt3[(size_t)z * DIM * DIM + (size_t)n * DIM + k] = __float2bfloat16(W[(size_t)k * DIM + n]);
  }
  if (tg < 2048) ((float4*)rowsum)[tg] = float4{0.f, 0.f, 0.f, 0.f};
}

__device__ __forceinline__ void phase1_body(
    int blk, int z, char* lds,
    const __hip_bfloat16* __restrict__ Xb, const __hip_bfloat16* __restrict__ Wt3,
    const float* __restrict__ bq, const float* __restrict__ bk,
    const float* __restrict__ bv,
    __hip_bfloat16* __restrict__ Qb, __hip_bfloat16* __restrict__ Kb,
    __hip_bfloat16* __restrict__ Vt)
{
  const int lane = threadIdx.x & 63, wid = threadIdx.x >> 6;
  const int wm = (wid & 1) * 64, wn = (wid >> 1) * 32;
  const int xt = blk >> 3, yt = blk & 7;     // 64 s-tiles x 8 d-tiles
  const __hip_bfloat16* A  = Xb + (size_t)xt * 128 * DIM;
  const __hip_bfloat16* Bt = Wt3 + (size_t)z * DIM * DIM + (size_t)yt * 64 * DIM;
  floatx4 acc[4][2] = {};
  gemm_dbuf<2>(A, DIM, Bt, DIM, DIM / 32, lds, acc);

  const float* bias = (z == 0) ? bq : (z == 1) ? bk : bv;
#pragma unroll
  for (int i = 0; i < 4; ++i) {
    const int mb = xt * 128 + wm + i * 16 + (lane >> 4) * 4;
#pragma unroll
    for (int j = 0; j < 2; ++j) {
      const int n = yt * 64 + wn + j * 16 + (lane & 15);
      const float bn = bias[n];
      if (z == 2) {
        const int b = mb >> 11, s = mb & 2047;
        ushort4 pk;
        pk.x = f2b(acc[i][j][0] + bn);
        pk.y = f2b(acc[i][j][1] + bn);
        pk.z = f2b(acc[i][j][2] + bn);
        pk.w = f2b(acc[i][j][3] + bn);
        *(ushort4*)((unsigned short*)Vt + ((size_t)b * DIM + n) * SEQ + s) = pk;
      } else {
        __hip_bfloat16* O = (z == 0) ? Qb : Kb;
#pragma unroll
        for (int r = 0; r < 4; ++r)
          O[(size_t)(mb + r) * DIM + n] = __float2bfloat16(acc[i][j][r] + bn);
      }
    }
  }
}

__device__ __forceinline__ void phase2_body(
    int job, char* lds,
    const __hip_bfloat16* __restrict__ Qb, const __hip_bfloat16* __restrict__ Kb,
    __hip_bfloat16* __restrict__ Sc, float* __restrict__ rowsum)
{
  const int lane = threadIdx.x & 63, wid = threadIdx.x >> 6;
  const int wm = (wid & 1) * 64, wn = (wid >> 1) * 64;
  const int b = job >> 8, rem = job & 255;
  const int xt = rem >> 4, yt = rem & 15;
  const __hip_bfloat16* A  = Qb + ((size_t)b * SEQ + (size_t)xt * 128) * DIM;
  const __hip_bfloat16* Bt = Kb + ((size_t)b * SEQ + (size_t)yt * 128) * DIM;
  floatx4 acc[4][4] = {};
  gemm_dbuf<4>(A, DIM, Bt, DIM, DIM / 32, lds, acc);

  __hip_bfloat16* O = Sc + (size_t)b * SEQ * SEQ;
  const float scale = 0.044194173824159216f;  // 1/sqrt(512)
#pragma unroll
  for (int i = 0; i < 4; ++i) {
    const int m = xt * 128 + wm + i * 16 + (lane >> 4) * 4;
#pragma unroll
    for (int j = 0; j < 4; ++j) {
      const int t = yt * 128 + wn + j * 16 + (lane & 15);
#pragma unroll
      for (int r = 0; r < 4; ++r) {
        acc[i][j][r] = __expf(acc[i][j][r] * scale);
        O[(size_t)(m + r) * SEQ + t] = __float2bfloat16(acc[i][j][r]);
      }
    }
  }
#pragma unroll
  for (int i = 0; i < 4; ++i) {
    const int mb = xt * 128 + wm + i * 16 + (lane >> 4) * 4;
#pragma unroll
    for (int r = 0; r < 4; ++r) {
      float s = (acc[i][0][r] + acc[i][1][r]) + (acc[i][2][r] + acc[i][3][r]);
      s += __shfl_xor(s, 1, 64);
      s += __shfl_xor(s, 2, 64);
      s += __shfl_xor(s, 4, 64);
      s += __shfl_xor(s, 8, 64);
      if ((lane & 15) == 0)
        atomicAdd(rowsum + b * SEQ + mb + r, s);
    }
  }
}

__device__ __forceinline__ void phase3_body(
    int blk, char* lds,
    const __hip_bfloat16* __restrict__ Sc, const __hip_bfloat16* __restrict__ Vt,
    const float* __restrict__ rowsum, float* __restrict__ out)
{
  const int lane = threadIdx.x & 63, wid = threadIdx.x >> 6;
  const int wm = (wid & 1) * 64, wn = (wid >> 1) * 32;
  const int b = blk >> 7, rem = blk & 127;
  const int xt = rem >> 3, yt = rem & 7;
  const __hip_bfloat16* A  = Sc + (size_t)b * SEQ * SEQ + (size_t)xt * 128 * SEQ;
  const __hip_bfloat16* Bt = Vt + (size_t)b * DIM * SEQ + (size_t)yt * 64 * SEQ;
  floatx4 acc[4][2] = {};
  gemm_dbuf<2>(A, SEQ, Bt, SEQ, SEQ / 32, lds, acc);

#pragma unroll
  for (int i = 0; i < 4; ++i) {
    const int m = xt * 128 + wm + i * 16 + (lane >> 4) * 4;
    const float4 rs = *(const float4*)(rowsum + b * SEQ + m);
    const float inv0 = 1.f / rs.x, inv1 = 1.f / rs.y, inv2 = 1.f / rs.z, inv3 = 1.f / rs.w;
#pragma unroll
    for (int j = 0; j < 2; ++j) {
      const int n = yt * 64 + wn + j * 16 + (lane & 15);
      float* o = out + ((size_t)b * SEQ + m) * DIM + n;
      o[0 * DIM] = acc[i][j][0] * inv0;
      o[1 * DIM] = acc[i][j][1] * inv1;
      o[2 * DIM] = acc[i][j][2] * inv2;
      o[3 * DIM] = acc[i][j][3] * inv3;
    }
  }
}

// ===================== cooperative single-dispatch kernel ==================
// __launch_bounds__(256, 2): min 2 waves/EU -> VGPR cap 256 -> 2 blocks/CU
// guaranteed (LDS 32KB -> 5/CU), so grid 512 is co-residency-safe.
__global__ __launch_bounds__(256, 2) void fused_attn(
    const float* __restrict__ X,  const float* __restrict__ Wq,
    const float* __restrict__ bq, const float* __restrict__ Wk,
    const float* __restrict__ bk, const float* __restrict__ Wv,
    const float* __restrict__ bv,
    __hip_bfloat16* __restrict__ Xb, __hip_bfloat16* __restrict__ Wt3,
    __hip_bfloat16* __restrict__ Qb, __hip_bfloat16* __restrict__ Kb,
    __hip_bfloat16* __restrict__ Vt, __hip_bfloat16* __restrict__ Sc,
    float* __restrict__ rowsum, float* __restrict__ out)
{
  __shared__ char lds[32768];
  cg::grid_group grid = cg::this_grid();
  const int blk = blockIdx.x;                 // 0..511

  phase0_body(blk, X, Wq, Wk, Wv, Xb, Wt3, rowsum);
  grid.sync();

  for (int z = 0; z < 3; ++z) {               // 1536 QKV jobs, 3 per block
    phase1_body(blk, z, lds, Xb, Wt3, bq, bk, bv, Qb, Kb, Vt);
    if (z < 2) __syncthreads();
  }
  grid.sync();

  for (int rep = 0; rep < 2; ++rep) {         // 1024 score jobs, 2 per block
    phase2_body(rep * 512 + blk, lds, Qb, Kb, Sc, rowsum);
    if (rep == 0) __syncthreads();
  }
  grid.sync();

  phase3_body(blk, lds, Sc, Vt, rowsum, out); // 512 PV jobs
}

// ===================== fallback kernels (plain launches) ===================
__global__ __launch_bounds__(256) void setup_kernel(
    const float* __restrict__ X, const float* __restrict__ Wq,
    const float* __restrict__ Wk, const float* __restrict__ Wv,
    __hip_bfloat16* __restrict__ Xb, __hip_bfloat16* __restrict__ Wt3,
    float* __restrict__ rowsum)
{
  phase0_body(blockIdx.x, X, Wq, Wk, Wv, Xb, Wt3, rowsum);
}

__global__ __launch_bounds__(256) void qkv_kernel(
    const __hip_bfloat16* __restrict__ Xb, const __hip_bfloat16* __restrict__ Wt3,
    const float* __restrict__ bq, const float* __restrict__ bk,
    const float* __restrict__ bv,
    __hip_bfloat16* __restrict__ Qb, __hip_bfloat16* __restrict__ Kb,
    __hip_bfloat16* __restrict__ Vt)
{
  __shared__ char lds[32768];
  phase1_body(blockIdx.x, blockIdx.y, lds, Xb, Wt3, bq, bk, bv, Qb, Kb, Vt);
}

__global__ __launch_bounds__(256) void scores_kernel(
    const __hip_bfloat16* __restrict__ Qb, const __hip_bfloat16* __restrict__ Kb,
    __hip_bfloat16* __restrict__ Sc, float* __restrict__ rowsum)
{
  __shared__ char lds[32768];
  phase2_body(blockIdx.x, lds, Qb, Kb, Sc, rowsum);
}

__global__ __launch_bounds__(256) void pv_kernel(
    const __hip_bfloat16* __restrict__ Sc, const __hip_bfloat16* __restrict__ Vt,
    const float* __restrict__ rowsum, float* __restrict__ out)
{
  __shared__ char lds[32768];
  phase3_body(blockIdx.x, lds, Sc, Vt, rowsum, out);
}

extern "C" void kernel_launch(void* const* d_in, const int* in_sizes, int n_in,
                              void* d_out, int out_size, void* d_ws, size_t ws_size,
                              hipStream_t stream) {
  const float* X  = (const float*)d_in[0];
  const float* Wq = (const float*)d_in[1];
  const float* bq = (const float*)d_in[2];
  const float* Wk = (const float*)d_in[3];
  const float* bk = (const float*)d_in[4];
  const float* Wv = (const float*)d_in[5];
  const float* bv = (const float*)d_in[6];
  float* out = (float*)d_out;
  char* ws = (char*)d_ws;

  __hip_bfloat16* Xb  = (__hip_bfloat16*)(ws + 0);           //  8 MB
  __hip_bfloat16* Wt3 = (__hip_bfloat16*)(ws + 8388608);     //  1.5 MB
  __hip_bfloat16* Qb  = (__hip_bfloat16*)(ws + 9961472);     //  8 MB
  __hip_bfloat16* Kb  = (__hip_bfloat16*)(ws + 18350080);    //  8 MB
  __hip_bfloat16* Vt  = (__hip_bfloat16*)(ws + 26738688);    //  8 MB
  __hip_bfloat16* Sc  = (__hip_bfloat16*)(ws + 35127296);    // 32 MB (exp scores)
  float*          rowsum = (float*)(ws + 68681728);          // 32 KB

  void* args[] = {
    (void*)&X, (void*)&Wq, (void*)&bq, (void*)&Wk, (void*)&bk,
    (void*)&Wv, (void*)&bv,
    (void*)&Xb, (void*)&Wt3, (void*)&Qb, (void*)&Kb, (void*)&Vt,
    (void*)&Sc, (void*)&rowsum, (void*)&out
  };
  hipError_t err = hipLaunchCooperativeKernel(
      (const void*)fused_attn, dim3(512), dim3(256), args, 0, stream);

  if (err != hipSuccess) {
    // fallback: identical phases as 4 plain launches
    setup_kernel<<<dim3(512), 256, 0, stream>>>(X, Wq, Wk, Wv, Xb, Wt3, rowsum);
    qkv_kernel<<<dim3(512, 3), 256, 0, stream>>>(Xb, Wt3, bq, bk, bv, Qb, Kb, Vt);
    scores_kernel<<<dim3(1024), 256, 0, stream>>>(Qb, Kb, Sc, rowsum);
    pv_kernel<<<dim3(512), 256, 0, stream>>>(Sc, Vt, rowsum, out);
  }
}

// Round 9
// 150.373 us; speedup vs baseline: 2.7242x; 2.7242x over previous
//
#include <hip/hip_runtime.h>
#include <hip/hip_bf16.h>
#include <stdint.h>

#define SEQ   2048
#define DIM   512
#define BATCH 4

typedef __attribute__((ext_vector_type(8))) short  short8;
typedef __attribute__((ext_vector_type(4))) float  floatx4;

static __device__ __forceinline__ unsigned short f2b(float f) {
  return __builtin_bit_cast(unsigned short, __float2bfloat16(f));
}

// async 16B/lane global->LDS (global_load_lds_dwordx4)
static __device__ __forceinline__ void gll16(const void* g, void* l) {
  __builtin_amdgcn_global_load_lds(
      (__attribute__((address_space(1))) void*)(uintptr_t)g,
      (__attribute__((address_space(3))) void*)l, 16, 0, 0);
}

// ---------------------------------------------------------------------------
// Fragment-linear layout (verified R4): logical [R rows][K] bf16 matrix as
// 1KB fragments of 16 rows x 32 k; frag index = rt*TK + kt; within a frag,
// lane l owns bytes l*16..l*16+15 = MFMA operand elements
//   row = rt*16 + (l&15), k = kt*32 + (l>>4)*8 + e.
// GEMM mainloop: LDS double-buffer, issue-early gll16 staging of whole
// fragments (contiguous 4KB per issue -> no strided L2 camping), LDS reads
// at frag_base + lane*16 (contiguous -> conflict-free), MFMA from LDS with
// full 4-wave sharing.
// ---------------------------------------------------------------------------

// BF = B fragments per K-step (8 -> 128x128 tile, 4 -> 128x64 tile).
// A fragments per K-step fixed at 8 (128 C-rows). 256 threads, 4 waves:
// wave w covers rows (w&1)*64..+63, cols (w>>1)*(BF*8)..(+BF*8-1).
template <int BF>
__device__ __forceinline__ void fgemm_lds(
    const char* __restrict__ A, int rtA0, int TKA,
    const char* __restrict__ B, int rtB0, int TKB,
    int kIters, char* lds, floatx4 (&acc)[4][BF / 2])
{
  constexpr int BUF = (8 + BF) * 1024;
  const int tid = threadIdx.x;
  const int w = tid >> 6, l = tid & 63;
  const int wmf = (w & 1) * 4;
  const int wnf = (w >> 1) * (BF / 2);

  auto stage = [&](int p, int kt) {
    char* dst = lds + p * BUF;
#pragma unroll
    for (int q = 0; q < 2; ++q) {                  // 8 A frags, 4 waves x 2
      const int f = q * 4 + w;
      gll16(A + (((size_t)(rtA0 + f) * TKA + kt) << 10) + l * 16,
            dst + f * 1024 + l * 16);
    }
#pragma unroll
    for (int q = 0; q < BF / 4; ++q) {             // BF B frags
      const int f = q * 4 + w;
      gll16(B + (((size_t)(rtB0 + f) * TKB + kt) << 10) + l * 16,
            dst + 8192 + f * 1024 + l * 16);
    }
  };

  stage(0, 0);
  __syncthreads();

  for (int kt = 0; kt < kIters; ++kt) {
    const int p = kt & 1;
    if (kt + 1 < kIters) stage(1 - p, kt + 1);     // issue-early prefetch

    const char* bA = lds + p * BUF;
    const char* bB = bA + 8192;
    short8 af[4], bf[BF / 2];
#pragma unroll
    for (int i = 0; i < 4; ++i)
      af[i] = *(const short8*)(bA + (wmf + i) * 1024 + l * 16);
#pragma unroll
    for (int j = 0; j < BF / 2; ++j)
      bf[j] = *(const short8*)(bB + (wnf + j) * 1024 + l * 16);

#pragma unroll
    for (int i = 0; i < 4; ++i)
#pragma unroll
      for (int j = 0; j < BF / 2; ++j)
        acc[i][j] = __builtin_amdgcn_mfma_f32_16x16x32_bf16(af[i], bf[j], acc[i][j], 0, 0, 0);

    __syncthreads();   // vmcnt(0) drain of prefetch + LDS reuse guard
  }
}

// ---- K0: setup: X->XbF frags, W->WF frags (transposed), zero rowsum -------
__global__ __launch_bounds__(256) void setup_kernel(
    const float* __restrict__ X, const float* __restrict__ Wq,
    const float* __restrict__ Wk, const float* __restrict__ Wv,
    short8* __restrict__ XbF, short8* __restrict__ WF,
    float* __restrict__ rowsum)
{
  const int flat = blockIdx.x * 256 + threadIdx.x;   // 0..524287
  {
    const int tile = flat >> 6, l = flat & 63;
    const int row = (tile >> 4) * 16 + (l & 15);
    const int k0  = (tile & 15) * 32 + (l >> 4) * 8;
    const float4 v0 = *(const float4*)(X + (size_t)row * DIM + k0);
    const float4 v1 = *(const float4*)(X + (size_t)row * DIM + k0 + 4);
    short8 o;
    o[0] = (short)f2b(v0.x); o[1] = (short)f2b(v0.y);
    o[2] = (short)f2b(v0.z); o[3] = (short)f2b(v0.w);
    o[4] = (short)f2b(v1.x); o[5] = (short)f2b(v1.y);
    o[6] = (short)f2b(v1.z); o[7] = (short)f2b(v1.w);
    XbF[flat] = o;
  }
  if (flat < 3 * 32768) {                            // W -> WF (rows=n, K=k)
    const int z = flat >> 15, within = flat & 32767;
    const float* W = (z == 0) ? Wq : (z == 1) ? Wk : Wv;
    const int tile = within >> 6, l = within & 63;
    const int n  = (tile >> 4) * 16 + (l & 15);
    const int k0 = (tile & 15) * 32 + (l >> 4) * 8;
    short8 o;
#pragma unroll
    for (int e = 0; e < 8; ++e)
      o[e] = (short)f2b(W[(size_t)(k0 + e) * DIM + n]);
    WF[flat] = o;
  }
  if (flat < 2048) ((float4*)rowsum)[flat] = float4{0.f, 0.f, 0.f, 0.f};
}

// ---- K1: QKV. z=0,1: C[d][s] (A=WF rows d, B=XbF rows s) -> QF/KF frags;
//      z=2: C[s][d] (A=XbF, B=WFv) -> VF frags (rows=d, K=t per batch). -----
__global__ __launch_bounds__(256) void qkv_kernel(
    const short8* __restrict__ XbF, const short8* __restrict__ WF,
    const float* __restrict__ bq, const float* __restrict__ bk,
    const float* __restrict__ bv,
    unsigned short* __restrict__ QF, unsigned short* __restrict__ KF,
    unsigned short* __restrict__ VF)
{
  __shared__ char lds[32768];
  const int z = blockIdx.z, x = blockIdx.x, y = blockIdx.y;
  const int lane = threadIdx.x & 63, w = threadIdx.x >> 6;
  const char* Xc = (const char*)XbF;
  const char* Wc = (const char*)WF;
  floatx4 acc[4][4] = {};

  if (z < 2) {
    fgemm_lds<8>(Wc + (size_t)z * 524288, y * 8, 16, Xc, x * 8, 16, 16, lds, acc);
    const float* bias = z ? bk : bq;
    unsigned short* OF = z ? KF : QF;
    const int dbase = y * 128 + (w & 1) * 64;
    const int sbase = x * 128 + (w >> 1) * 64;
#pragma unroll
    for (int i = 0; i < 4; ++i) {
      const int d0 = dbase + i * 16 + (lane >> 4) * 4;
      const float4 b4 = *(const float4*)(bias + d0);
#pragma unroll
      for (int j = 0; j < 4; ++j) {
        const int s = sbase + j * 16 + (lane & 15);
        ushort4 pk;
        pk.x = f2b(acc[i][j][0] + b4.x);
        pk.y = f2b(acc[i][j][1] + b4.y);
        pk.z = f2b(acc[i][j][2] + b4.z);
        pk.w = f2b(acc[i][j][3] + b4.w);
        *(ushort4*)(OF + (size_t)((s >> 4) * 16 + (d0 >> 5)) * 512 +
                    ((((d0 & 31) >> 3) << 4) | (s & 15)) * 8 + (d0 & 7)) = pk;
      }
    }
  } else {
    fgemm_lds<8>(Xc, x * 8, 16, Wc + 2 * 524288, y * 8, 16, 16, lds, acc);
    const int sbase = x * 128 + (w & 1) * 64;
    const int dbase = y * 128 + (w >> 1) * 64;
#pragma unroll
    for (int i = 0; i < 4; ++i) {
      const int s0 = sbase + i * 16 + (lane >> 4) * 4;
      const int bt = s0 >> 11, t0 = s0 & 2047;
#pragma unroll
      for (int j = 0; j < 4; ++j) {
        const int d = dbase + j * 16 + (lane & 15);
        const float bn = bv[d];
        ushort4 pk;
        pk.x = f2b(acc[i][j][0] + bn);
        pk.y = f2b(acc[i][j][1] + bn);
        pk.z = f2b(acc[i][j][2] + bn);
        pk.w = f2b(acc[i][j][3] + bn);
        *(ushort4*)(VF + (size_t)bt * DIM * SEQ +
                    (size_t)((d >> 4) * 64 + (t0 >> 5)) * 512 +
                    ((((t0 & 31) >> 3) << 4) | (d & 15)) * 8 + (t0 & 7)) = pk;
      }
    }
  }
}

// ---- K2: S^T = K Q^T; epilogue exp(*scale) -> ScF frags + rowsum atomics --
__global__ __launch_bounds__(256) void scores_kernel(
    const unsigned short* __restrict__ QF, const unsigned short* __restrict__ KF,
    unsigned short* __restrict__ ScF, float* __restrict__ rowsum)
{
  __shared__ char lds[32768];
  const int b = blockIdx.z, x = blockIdx.x, y = blockIdx.y;
  const int lane = threadIdx.x & 63, w = threadIdx.x >> 6;
  floatx4 acc[4][4] = {};
  fgemm_lds<8>((const char*)KF + (size_t)b * 2097152, y * 8, 16,
               (const char*)QF + (size_t)b * 2097152, x * 8, 16, 16, lds, acc);

  unsigned short* S = ScF + (size_t)b * SEQ * SEQ;
  const float scale = 0.044194173824159216f;  // 1/sqrt(512)
  const int tb = y * 128 + (w & 1) * 64;
  const int sb = x * 128 + (w >> 1) * 64;
  float colsum[4] = {0.f, 0.f, 0.f, 0.f};
#pragma unroll
  for (int i = 0; i < 4; ++i) {
    const int t0 = tb + i * 16 + (lane >> 4) * 4;
#pragma unroll
    for (int j = 0; j < 4; ++j) {
      const int s = sb + j * 16 + (lane & 15);
      float e0 = __expf(acc[i][j][0] * scale);
      float e1 = __expf(acc[i][j][1] * scale);
      float e2 = __expf(acc[i][j][2] * scale);
      float e3 = __expf(acc[i][j][3] * scale);
      colsum[j] += (e0 + e1) + (e2 + e3);
      ushort4 pk;
      pk.x = f2b(e0); pk.y = f2b(e1); pk.z = f2b(e2); pk.w = f2b(e3);
      *(ushort4*)(S + (size_t)((s >> 4) * 64 + (t0 >> 5)) * 512 +
                  ((((t0 & 31) >> 3) << 4) | (s & 15)) * 8 + (t0 & 7)) = pk;
    }
  }
#pragma unroll
  for (int j = 0; j < 4; ++j) {
    colsum[j] += __shfl_xor(colsum[j], 16, 64);
    colsum[j] += __shfl_xor(colsum[j], 32, 64);
  }
  if (lane < 16) {
#pragma unroll
    for (int j = 0; j < 4; ++j)
      atomicAdd(rowsum + b * SEQ + sb + j * 16 + lane, colsum[j]);
  }
}

// ---- K3: out[s][d] = (ScF . VF) / rowsum[s]; 128s x 64d tiles -------------
__global__ __launch_bounds__(256) void pv_kernel(
    const unsigned short* __restrict__ ScF, const unsigned short* __restrict__ VF,
    const float* __restrict__ rowsum, float* __restrict__ out)
{
  __shared__ char lds[24576];
  const int b = blockIdx.z, x = blockIdx.x, y = blockIdx.y;
  const int lane = threadIdx.x & 63, w = threadIdx.x >> 6;
  floatx4 acc[4][2] = {};
  fgemm_lds<4>((const char*)ScF + (size_t)b * 8388608, x * 8, 64,
               (const char*)VF + (size_t)b * 2097152, y * 4, 64, 64, lds, acc);

#pragma unroll
  for (int i = 0; i < 4; ++i) {
    const int m0 = x * 128 + (w & 1) * 64 + i * 16 + (lane >> 4) * 4;
    const float4 rs = *(const float4*)(rowsum + b * SEQ + m0);
    const float inv0 = 1.f / rs.x, inv1 = 1.f / rs.y, inv2 = 1.f / rs.z, inv3 = 1.f / rs.w;
#pragma unroll
    for (int j = 0; j < 2; ++j) {
      const int d = y * 64 + (w >> 1) * 32 + j * 16 + (lane & 15);
      float* o = out + ((size_t)b * SEQ + m0) * DIM + d;
      o[0 * DIM] = acc[i][j][0] * inv0;
      o[1 * DIM] = acc[i][j][1] * inv1;
      o[2 * DIM] = acc[i][j][2] * inv2;
      o[3 * DIM] = acc[i][j][3] * inv3;
    }
  }
}

extern "C" void kernel_launch(void* const* d_in, const int* in_sizes, int n_in,
                              void* d_out, int out_size, void* d_ws, size_t ws_size,
                              hipStream_t stream) {
  const float* X  = (const float*)d_in[0];
  const float* Wq = (const float*)d_in[1];
  const float* bq = (const float*)d_in[2];
  const float* Wk = (const float*)d_in[3];
  const float* bk = (const float*)d_in[4];
  const float* Wv = (const float*)d_in[5];
  const float* bv = (const float*)d_in[6];
  float* out = (float*)d_out;
  char* ws = (char*)d_ws;

  // workspace layout (bytes)
  short8* XbF = (short8*)(ws + 0);                    //  8 MB   (rows=b*S+s, K=512)
  short8* WF  = (short8*)(ws + 8388608);              //  1.5 MB (rows=n, K=512, x3)
  char*   QF  = ws + 9961472;                         //  8 MB   (rows=s, K=d)
  char*   KF  = ws + 18350080;                        //  8 MB   (rows=s, K=d)
  char*   VF  = ws + 26738688;                        //  8 MB   (rows=d, K=t, per b)
  char*   ScF = ws + 35127296;                        // 32 MB   (rows=s, K=t, per b)
  float*  rowsum = (float*)(ws + 68681728);           // 32 KB

  setup_kernel<<<dim3(2048), 256, 0, stream>>>(X, Wq, Wk, Wv, XbF, WF, rowsum);
  qkv_kernel<<<dim3(64, 4, 3), 256, 0, stream>>>(
      XbF, WF, bq, bk, bv,
      (unsigned short*)QF, (unsigned short*)KF, (unsigned short*)VF);
  scores_kernel<<<dim3(16, 16, 4), 256, 0, stream>>>(
      (const unsigned short*)QF, (const unsigned short*)KF,
      (unsigned short*)ScF, rowsum);
  pv_kernel<<<dim3(16, 8, 4), 256, 0, stream>>>(
      (const unsigned short*)ScF, (const unsigned short*)VF, rowsum, out);
}

// Round 10
// 150.197 us; speedup vs baseline: 2.7274x; 1.0012x over previous
//
#include <hip/hip_runtime.h>
#include <hip/hip_bf16.h>
#include <stdint.h>

#define SEQ   2048
#define DIM   512
#define BATCH 4

typedef __attribute__((ext_vector_type(8))) short  short8;
typedef __attribute__((ext_vector_type(4))) float  floatx4;

static __device__ __forceinline__ unsigned short f2b(float f) {
  return __builtin_bit_cast(unsigned short, __float2bfloat16(f));
}

// async 16B/lane global->LDS (global_load_lds_dwordx4)
static __device__ __forceinline__ void gll16(const void* g, void* l) {
  __builtin_amdgcn_global_load_lds(
      (__attribute__((address_space(1))) void*)(uintptr_t)g,
      (__attribute__((address_space(3))) void*)l, 16, 0, 0);
}

// ---------------------------------------------------------------------------
// Fragment-linear layout (verified R4/R9): logical [R rows][K] bf16 matrix as
// 1KB fragments of 16 rows x 32 k; frag index = rt*TK + kt; within a frag,
// lane l owns bytes l*16..+15 = MFMA operand row rt*16+(l&15), k octet (l>>4).
// ---------------------------------------------------------------------------

// 8-wave (512-thread) fragment GEMM with LDS double-buffer + issue-early
// staging. AF/BF = A/B fragments per K-column (16 rows each); WM x WN = 8
// waves; KC = frag columns per K-step (BK = KC*32).
// Per K-step: stage (AF+BF)*KC KB, AF*BF*KC MFMA per block -> one barrier.
template <int AF, int BF, int WM, int WN, int KC>
__device__ __forceinline__ void fgemm8(
    const char* __restrict__ A, int rtA0, int TKA,
    const char* __restrict__ B, int rtB0, int TKB,
    int kIters, char* lds, floatx4 (&acc)[AF / WM][BF / WN])
{
  constexpr int AWF = AF / WM, BWF = BF / WN;
  constexpr int BUF = (AF + BF) * KC * 1024;
  const int tid = threadIdx.x;
  const int w = tid >> 6, l = tid & 63;
  const int wm = w % WM, wn = w / WM;

  auto stage = [&](int p, int kt) {
    char* dst = lds + p * BUF;
#pragma unroll
    for (int c = 0; c < KC; ++c) {
#pragma unroll
      for (int q = 0; q < AF / 8; ++q) {
        const int f = q * 8 + w;
        gll16(A + (((size_t)(rtA0 + f) * TKA + kt * KC + c) << 10) + l * 16,
              dst + (c * AF + f) * 1024 + l * 16);
      }
#pragma unroll
      for (int q = 0; q < BF / 8; ++q) {
        const int f = q * 8 + w;
        gll16(B + (((size_t)(rtB0 + f) * TKB + kt * KC + c) << 10) + l * 16,
              dst + (KC * AF + c * BF + f) * 1024 + l * 16);
      }
    }
  };

  stage(0, 0);
  __syncthreads();

  for (int kt = 0; kt < kIters; ++kt) {
    const int p = kt & 1;
    if (kt + 1 < kIters) stage(1 - p, kt + 1);   // issue-early prefetch

    const char* bA = lds + p * BUF;
    const char* bB = bA + KC * AF * 1024;
    short8 af[KC][AWF], bf[KC][BWF];
#pragma unroll
    for (int c = 0; c < KC; ++c) {
#pragma unroll
      for (int i = 0; i < AWF; ++i)
        af[c][i] = *(const short8*)(bA + (c * AF + wm * AWF + i) * 1024 + l * 16);
#pragma unroll
      for (int j = 0; j < BWF; ++j)
        bf[c][j] = *(const short8*)(bB + (c * BF + wn * BWF + j) * 1024 + l * 16);
    }
#pragma unroll
    for (int c = 0; c < KC; ++c)
#pragma unroll
      for (int i = 0; i < AWF; ++i)
#pragma unroll
        for (int j = 0; j < BWF; ++j)
          acc[i][j] = __builtin_amdgcn_mfma_f32_16x16x32_bf16(af[c][i], bf[c][j], acc[i][j], 0, 0, 0);

    __syncthreads();   // drain prefetch + LDS reuse guard (one per K-step)
  }
}

// ---- K0: setup: X->XbF frags, W->WF frags (transposed), zero rowsum -------
__global__ __launch_bounds__(256) void setup_kernel(
    const float* __restrict__ X, const float* __restrict__ Wq,
    const float* __restrict__ Wk, const float* __restrict__ Wv,
    short8* __restrict__ XbF, short8* __restrict__ WF,
    float* __restrict__ rowsum)
{
  const int flat = blockIdx.x * 256 + threadIdx.x;   // 0..524287
  {
    const int tile = flat >> 6, l = flat & 63;
    const int row = (tile >> 4) * 16 + (l & 15);
    const int k0  = (tile & 15) * 32 + (l >> 4) * 8;
    const float4 v0 = *(const float4*)(X + (size_t)row * DIM + k0);
    const float4 v1 = *(const float4*)(X + (size_t)row * DIM + k0 + 4);
    short8 o;
    o[0] = (short)f2b(v0.x); o[1] = (short)f2b(v0.y);
    o[2] = (short)f2b(v0.z); o[3] = (short)f2b(v0.w);
    o[4] = (short)f2b(v1.x); o[5] = (short)f2b(v1.y);
    o[6] = (short)f2b(v1.z); o[7] = (short)f2b(v1.w);
    XbF[flat] = o;
  }
  if (flat < 3 * 32768) {                            // W -> WF (rows=n, K=k)
    const int z = flat >> 15, within = flat & 32767;
    const float* W = (z == 0) ? Wq : (z == 1) ? Wk : Wv;
    const int tile = within >> 6, l = within & 63;
    const int n  = (tile >> 4) * 16 + (l & 15);
    const int k0 = (tile & 15) * 32 + (l >> 4) * 8;
    short8 o;
#pragma unroll
    for (int e = 0; e < 8; ++e)
      o[e] = (short)f2b(W[(size_t)(k0 + e) * DIM + n]);
    WF[flat] = o;
  }
  if (flat < 2048) ((float4*)rowsum)[flat] = float4{0.f, 0.f, 0.f, 0.f};
}

// ---- K1: QKV. z=0,1: C[d][s] 256d x 128s (A=WF, B=XbF) -> QF/KF frags;
//      z=2: C[s][d] 256s x 128d (A=XbF, B=WFv) -> VF frags. 8 waves. --------
__global__ __launch_bounds__(512, 2) void qkv_kernel(
    const short8* __restrict__ XbF, const short8* __restrict__ WF,
    const float* __restrict__ bq, const float* __restrict__ bk,
    const float* __restrict__ bv,
    unsigned short* __restrict__ QF, unsigned short* __restrict__ KF,
    unsigned short* __restrict__ VF)
{
  __shared__ char lds[49152];   // 2 x (16+8) KB
  const int z = blockIdx.z, job = blockIdx.x;    // 0..127
  const int lane = threadIdx.x & 63, w = threadIdx.x >> 6;
  const int wm = w & 3, wn = w >> 2;             // WM=4, WN=2
  const char* Xc = (const char*)XbF;
  const char* Wc = (const char*)WF;
  floatx4 acc[4][4] = {};

  if (z < 2) {
    const int x = job & 63, y = job >> 6;        // s-tile(128), d-tile(256)
    fgemm8<16, 8, 4, 2, 1>(Wc + (size_t)z * 524288, y * 16, 16,
                           Xc, x * 8, 16, 16, lds, acc);
    const float* bias = z ? bk : bq;
    unsigned short* OF = z ? KF : QF;
    const int dbase = y * 256 + wm * 64;
    const int sbase = x * 128 + wn * 64;
#pragma unroll
    for (int i = 0; i < 4; ++i) {
      const int d0 = dbase + i * 16 + (lane >> 4) * 4;
      const float4 b4 = *(const float4*)(bias + d0);
#pragma unroll
      for (int j = 0; j < 4; ++j) {
        const int s = sbase + j * 16 + (lane & 15);
        ushort4 pk;
        pk.x = f2b(acc[i][j][0] + b4.x);
        pk.y = f2b(acc[i][j][1] + b4.y);
        pk.z = f2b(acc[i][j][2] + b4.z);
        pk.w = f2b(acc[i][j][3] + b4.w);
        *(ushort4*)(OF + (size_t)((s >> 4) * 16 + (d0 >> 5)) * 512 +
                    ((((d0 & 31) >> 3) << 4) | (s & 15)) * 8 + (d0 & 7)) = pk;
      }
    }
  } else {
    const int x = job >> 2, y = job & 3;         // s-tile(256) x32, d-tile(128) x4
    fgemm8<16, 8, 4, 2, 1>(Xc, x * 16, 16,
                           Wc + 2 * 524288, y * 8, 16, 16, lds, acc);
    const int sbase = x * 256 + wm * 64;
    const int dbase = y * 128 + wn * 64;
#pragma unroll
    for (int i = 0; i < 4; ++i) {
      const int s0 = sbase + i * 16 + (lane >> 4) * 4;
      const int bt = s0 >> 11, t0 = s0 & 2047;
#pragma unroll
      for (int j = 0; j < 4; ++j) {
        const int d = dbase + j * 16 + (lane & 15);
        const float bn = bv[d];
        ushort4 pk;
        pk.x = f2b(acc[i][j][0] + bn);
        pk.y = f2b(acc[i][j][1] + bn);
        pk.z = f2b(acc[i][j][2] + bn);
        pk.w = f2b(acc[i][j][3] + bn);
        *(ushort4*)(VF + (size_t)bt * DIM * SEQ +
                    (size_t)((d >> 4) * 64 + (t0 >> 5)) * 512 +
                    ((((t0 & 31) >> 3) << 4) | (d & 15)) * 8 + (t0 & 7)) = pk;
      }
    }
  }
}

// ---- K2: S^T = K Q^T, 256t x 256s tiles; exp epilogue -> ScF + rowsum -----
__global__ __launch_bounds__(512, 2) void scores_kernel(
    const unsigned short* __restrict__ QF, const unsigned short* __restrict__ KF,
    unsigned short* __restrict__ ScF, float* __restrict__ rowsum)
{
  __shared__ char lds[65536];   // 2 x 32 KB
  const int b = blockIdx.z, x = blockIdx.x, y = blockIdx.y;
  const int lane = threadIdx.x & 63, w = threadIdx.x >> 6;
  const int wm = w & 1, wn = w >> 1;             // WM=2, WN=4
  floatx4 acc[8][4] = {};
  fgemm8<16, 16, 2, 4, 1>((const char*)KF + (size_t)b * 2097152, y * 16, 16,
                          (const char*)QF + (size_t)b * 2097152, x * 16, 16,
                          16, lds, acc);

  unsigned short* S = ScF + (size_t)b * SEQ * SEQ;
  const float scale = 0.044194173824159216f;  // 1/sqrt(512)
  const int tbase = y * 256 + wm * 128;
  const int sbase = x * 256 + wn * 64;
  float colsum[4] = {0.f, 0.f, 0.f, 0.f};
#pragma unroll
  for (int i = 0; i < 8; ++i) {
    const int t0 = tbase + i * 16 + (lane >> 4) * 4;
#pragma unroll
    for (int j = 0; j < 4; ++j) {
      const int s = sbase + j * 16 + (lane & 15);
      float e0 = __expf(acc[i][j][0] * scale);
      float e1 = __expf(acc[i][j][1] * scale);
      float e2 = __expf(acc[i][j][2] * scale);
      float e3 = __expf(acc[i][j][3] * scale);
      colsum[j] += (e0 + e1) + (e2 + e3);
      ushort4 pk;
      pk.x = f2b(e0); pk.y = f2b(e1); pk.z = f2b(e2); pk.w = f2b(e3);
      *(ushort4*)(S + (size_t)((s >> 4) * 64 + (t0 >> 5)) * 512 +
                  ((((t0 & 31) >> 3) << 4) | (s & 15)) * 8 + (t0 & 7)) = pk;
    }
  }
#pragma unroll
  for (int j = 0; j < 4; ++j) {
    colsum[j] += __shfl_xor(colsum[j], 16, 64);
    colsum[j] += __shfl_xor(colsum[j], 32, 64);
  }
  if (lane < 16) {
#pragma unroll
    for (int j = 0; j < 4; ++j)
      atomicAdd(rowsum + b * SEQ + sbase + j * 16 + lane, colsum[j]);
  }
}

// ---- K3: out[s][d] = (ScF . VF) / rowsum[s]; 128x128 tile, BK=64 ----------
__global__ __launch_bounds__(512, 2) void pv_kernel(
    const unsigned short* __restrict__ ScF, const unsigned short* __restrict__ VF,
    const float* __restrict__ rowsum, float* __restrict__ out)
{
  __shared__ char lds[65536];   // 2 x (8+8)*2 KB
  const int b = blockIdx.z, x = blockIdx.x, y = blockIdx.y;
  const int lane = threadIdx.x & 63, w = threadIdx.x >> 6;
  const int wm = w & 1, wn = w >> 1;             // WM=2, WN=4
  floatx4 acc[4][2] = {};
  fgemm8<8, 8, 2, 4, 2>((const char*)ScF + (size_t)b * 8388608, x * 8, 64,
                        (const char*)VF + (size_t)b * 2097152, y * 8, 64,
                        32, lds, acc);

  const int mbase = x * 128 + wm * 64;
  const int dbase = y * 128 + wn * 32;
#pragma unroll
  for (int i = 0; i < 4; ++i) {
    const int m0 = mbase + i * 16 + (lane >> 4) * 4;
    const float4 rs = *(const float4*)(rowsum + b * SEQ + m0);
    const float inv0 = 1.f / rs.x, inv1 = 1.f / rs.y, inv2 = 1.f / rs.z, inv3 = 1.f / rs.w;
#pragma unroll
    for (int j = 0; j < 2; ++j) {
      const int d = dbase + j * 16 + (lane & 15);
      float* o = out + ((size_t)b * SEQ + m0) * DIM + d;
      o[0 * DIM] = acc[i][j][0] * inv0;
      o[1 * DIM] = acc[i][j][1] * inv1;
      o[2 * DIM] = acc[i][j][2] * inv2;
      o[3 * DIM] = acc[i][j][3] * inv3;
    }
  }
}

extern "C" void kernel_launch(void* const* d_in, const int* in_sizes, int n_in,
                              void* d_out, int out_size, void* d_ws, size_t ws_size,
                              hipStream_t stream) {
  const float* X  = (const float*)d_in[0];
  const float* Wq = (const float*)d_in[1];
  const float* bq = (const float*)d_in[2];
  const float* Wk = (const float*)d_in[3];
  const float* bk = (const float*)d_in[4];
  const float* Wv = (const float*)d_in[5];
  const float* bv = (const float*)d_in[6];
  float* out = (float*)d_out;
  char* ws = (char*)d_ws;

  // workspace layout (bytes)
  short8* XbF = (short8*)(ws + 0);                    //  8 MB   (rows=b*S+s, K=512)
  short8* WF  = (short8*)(ws + 8388608);              //  1.5 MB (rows=n, K=512, x3)
  char*   QF  = ws + 9961472;                         //  8 MB   (rows=s, K=d)
  char*   KF  = ws + 18350080;                        //  8 MB   (rows=s, K=d)
  char*   VF  = ws + 26738688;                        //  8 MB   (rows=d, K=t, per b)
  char*   ScF = ws + 35127296;                        // 32 MB   (rows=s, K=t, per b)
  float*  rowsum = (float*)(ws + 68681728);           // 32 KB

  setup_kernel<<<dim3(2048), 256, 0, stream>>>(X, Wq, Wk, Wv, XbF, WF, rowsum);
  qkv_kernel<<<dim3(128, 1, 3), 512, 0, stream>>>(
      XbF, WF, bq, bk, bv,
      (unsigned short*)QF, (unsigned short*)KF, (unsigned short*)VF);
  scores_kernel<<<dim3(8, 8, 4), 512, 0, stream>>>(
      (const unsigned short*)QF, (const unsigned short*)KF,
      (unsigned short*)ScF, rowsum);
  pv_kernel<<<dim3(16, 4, 4), 512, 0, stream>>>(
      (const unsigned short*)ScF, (const unsigned short*)VF, rowsum, out);
}